// Round 11
// baseline (627.725 us; speedup 1.0000x reference)
//
#include <hip/hip_runtime.h>
#include <hip/hip_bf16.h>
#include <math.h>

// GoldenMoE: B=2,T=2048,D=2048,E=8,F=2048.
// Round 11: r10 + materialized A-gather (xg[e][pos][2048] bf16, contiguous
// staging in fused_gu — same pattern as down). 3-tier ws branch:
// FULL_XG (contig) > FULL (r10 gathered) > per-expert fallback.

#define E_NUM 8
#define BT_NUM 4096
#define MAT_ELEMS ((size_t)2048 * 2048)
#define MAXT 136

typedef short short8 __attribute__((ext_vector_type(8)));
typedef short short2v __attribute__((ext_vector_type(2)));
typedef float f32x4 __attribute__((ext_vector_type(4)));
typedef __bf16 bf16x8 __attribute__((ext_vector_type(8)));

__device__ __forceinline__ short f2bf(float f) {
  __hip_bfloat16 h = __float2bfloat16(f);
  return __builtin_bit_cast(short, h);
}
__device__ __forceinline__ float bf2f(short s) {
  __hip_bfloat16 h = __builtin_bit_cast(__hip_bfloat16, s);
  return __bfloat162float(h);
}

#define GLOAD_LDS(gptr, lptr) \
  __builtin_amdgcn_global_load_lds( \
      (const __attribute__((address_space(1))) unsigned int*)(gptr), \
      (__attribute__((address_space(3))) unsigned int*)(lptr), 16, 0, 0)

#define LDS_OFF(p) ((unsigned)(size_t)(__attribute__((address_space(3))) const short*)(p))

#define DS_READ_B128(d, a) \
  asm volatile("ds_read_b128 %0, %1" : "=v"(d) : "v"(a))

#define BAR() __builtin_amdgcn_s_barrier()
#define LGKM0() do { \
  asm volatile("s_waitcnt lgkmcnt(0)" ::: "memory"); \
  __builtin_amdgcn_sched_barrier(0); \
} while (0)
#define VMC(n) asm volatile("s_waitcnt vmcnt(" #n ")" ::: "memory")

// XCD-bijective unmap
__device__ __forceinline__ int xcd_unmap(int o, int nact) {
  const int q = nact >> 3, rr = nact & 7;
  const int xcd = o & 7, seq = o >> 3;
  return (xcd < rr) ? xcd * (q + 1) + seq
                    : rr * (q + 1) + (xcd - rr) * q + seq;
}

// ---------------- router ----------------
__global__ __launch_bounds__(256) void router_kernel(
    const float* __restrict__ x, const float* __restrict__ Wr,
    const float* __restrict__ temp, float* __restrict__ rw)
{
  const int bt = blockIdx.x;
  const int tid = threadIdx.x;
  const float* xp = x + (size_t)bt * 2048;
  float acc[E_NUM];
#pragma unroll
  for (int e = 0; e < E_NUM; e++) acc[e] = 0.f;
  for (int d = tid; d < 2048; d += 256) {
    float xv = xp[d];
    const float* wr = Wr + (size_t)d * E_NUM;
#pragma unroll
    for (int e = 0; e < E_NUM; e++) acc[e] += xv * wr[e];
  }
#pragma unroll
  for (int e = 0; e < E_NUM; e++) {
    float v = acc[e];
#pragma unroll
    for (int off = 32; off > 0; off >>= 1) v += __shfl_down(v, off, 64);
    acc[e] = v;
  }
  __shared__ float part[4][E_NUM];
  const int wid = tid >> 6, lane = tid & 63;
  if (lane == 0) {
#pragma unroll
    for (int e = 0; e < E_NUM; e++) part[wid][e] = acc[e];
  }
  __syncthreads();
  if (tid == 0) {
    const float t = temp[0];
    float wz[E_NUM], fb[E_NUM];
    float wsum = 0.f;
#pragma unroll
    for (int e = 0; e < E_NUM; e++) {
      float l = part[0][e] + part[1][e] + part[2][e] + part[3][e];
      float ih = 1.f / (1.f + expf(-l / t));
      float ds = fabsf(ih - 0.36787944117144233f);
      float in_zone = (ih >= 0.21231792754821915f && ih <= 0.5f) ? 1.f : 0.f;
      wz[e] = expf(-ds / 0.1f) * in_zone;
      wsum += wz[e];
      fb[e] = expf(-ds / 0.3f);
    }
    float w[E_NUM];
    if (wsum < 1e-8f) {
      int i1 = 0;
#pragma unroll
      for (int e = 1; e < E_NUM; e++) if (fb[e] > fb[i1]) i1 = e;
      int i2 = -1;
#pragma unroll
      for (int e = 0; e < E_NUM; e++) if (e != i1 && (i2 < 0 || fb[e] > fb[i2])) i2 = e;
      float s = fmaxf(fb[i1] + fb[i2], 1e-8f);
#pragma unroll
      for (int e = 0; e < E_NUM; e++) w[e] = (e == i1 || e == i2) ? fb[e] / s : 0.f;
    } else {
#pragma unroll
      for (int e = 0; e < E_NUM; e++) w[e] = wz[e];
    }
    float s2 = 0.f;
#pragma unroll
    for (int e = 0; e < E_NUM; e++) s2 += w[e];
    s2 = fmaxf(s2, 1e-8f);
    float inv = 1.f / s2;
#pragma unroll
    for (int e = 0; e < E_NUM; e++) rw[(size_t)bt * E_NUM + e] = w[e] * inv;
  }
}

// ---------------- sparse bookkeeping ----------------
__global__ void init_cnt_kernel(int* __restrict__ cnt) {
  if (threadIdx.x < 32) cnt[threadIdx.x] = 0;
}

__global__ __launch_bounds__(256) void build_idx_kernel(
    const float* __restrict__ rw, int* __restrict__ cnt,
    unsigned short* __restrict__ idx,
    unsigned short* __restrict__ inv, unsigned char* __restrict__ invn)
{
  const int t = blockIdx.x * 256 + threadIdx.x;
  const float* w = rw + (size_t)t * E_NUM;
  int s = 0;
#pragma unroll
  for (int e = 0; e < E_NUM; e++) {
    if (w[e] != 0.f) {
      int p = atomicAdd(&cnt[e], 1);
      idx[(size_t)e * BT_NUM + p] = (unsigned short)t;
      inv[(size_t)t * E_NUM + s] = (unsigned short)((e << 12) | p);
      s++;
    }
  }
  invn[t] = (unsigned char)s;
}

__global__ void pack_tiles_kernel(int* __restrict__ cnt) {
  if (threadIdx.x == 0) {
    int n = 0;
    for (int e = 0; e < E_NUM; e++) {
      const int nt = (cnt[e] + 255) >> 8;
      for (int by = 0; by < nt; by++) cnt[32 + n++] = (e << 8) | by;
    }
    cnt[16] = n;
  }
}

__global__ __launch_bounds__(256) void zero_out_kernel(float* __restrict__ out) {
  const size_t i = ((size_t)blockIdx.x * 256 + threadIdx.x) * 4;
  *(f32x4*)(out + i) = (f32x4){0.f, 0.f, 0.f, 0.f};
}

// ---------------- x f32 -> bf16 (dense, for non-XG paths) ----------------
__global__ __launch_bounds__(256) void cvt_x_kernel(
    const float* __restrict__ x, short* __restrict__ xb)
{
  const size_t base = ((size_t)blockIdx.x * 256 + threadIdx.x) * 8;
  f32x4 v0 = *(const f32x4*)(x + base);
  f32x4 v1 = *(const f32x4*)(x + base + 4);
  short8 p;
#pragma unroll
  for (int j = 0; j < 4; j++) { p[j] = f2bf(v0[j]); p[4 + j] = f2bf(v1[j]); }
  *(short8*)(xb + base) = p;
}

// ---------------- gather x -> compact per-expert xg (bf16) ----------------
// One block per packed M-tile: 256 rows, each row 2048 f32 -> bf16.
__global__ __launch_bounds__(256) void gather_x_kernel(
    const float* __restrict__ x, const unsigned short* __restrict__ idx,
    const int* __restrict__ cnt, short* __restrict__ xg)
{
  const int nt = cnt[16];
  if ((int)blockIdx.x >= nt) return;
  const int tl = cnt[32 + blockIdx.x];
  const int e = tl >> 8, by = tl & 255;
  const int cntE = cnt[e];
  const int m0 = by * 256;
  const int cm = cntE - 1;
  const unsigned short* idxe = idx + (size_t)e * BT_NUM;
  short* xge = xg + (size_t)e * BT_NUM * 2048;
  const int c = threadIdx.x * 8;
  for (int rloc = 0; rloc < 256; rloc++) {
    const int row = m0 + rloc;
    const int tok = idxe[min(row, cm)];
    const float* sp = x + (size_t)tok * 2048 + c;
    f32x4 v0 = *(const f32x4*)sp;
    f32x4 v1 = *(const f32x4*)(sp + 4);
    short8 p;
#pragma unroll
    for (int j = 0; j < 4; j++) { p[j] = f2bf(v0[j]); p[4 + j] = f2bf(v1[j]); }
    *(short8*)&xge[(size_t)row * 2048 + c] = p;
  }
}

// ------------- transpose + f32->bf16 (64x32 tile, short2 writes) -------------
__global__ __launch_bounds__(256) void transpose_cvt_kernel(
    const float* __restrict__ sg, const float* __restrict__ su, const float* __restrict__ sd,
    short* __restrict__ dgu, short* __restrict__ dd, int nexp)
{
  const int which = blockIdx.z / nexp, e = blockIdx.z % nexp;
  __shared__ float t[32][65];
  const int tx = threadIdx.x, ty = threadIdx.y;
  const int x0 = blockIdx.x * 32, y0 = blockIdx.y * 64;
  const float* s = (which == 0 ? sg : which == 1 ? su : sd) + (size_t)e * MAT_ELEMS;
#pragma unroll
  for (int i = 0; i < 8; i++)
    t[tx][ty + 8 * i] = s[(size_t)(y0 + ty + 8 * i) * 2048 + x0 + tx];
  __syncthreads();
  if (which < 2) {
    short* d = dgu + (size_t)e * (2 * MAT_ELEMS);
#pragma unroll
    for (int i = 0; i < 4; i++) {
      const int row = ty + 8 * i;
      const int col = x0 + row;
      const int np = ((col >> 5) * 64) + which * 32 + (col & 31);
      short2v v = {f2bf(t[row][2 * tx]), f2bf(t[row][2 * tx + 1])};
      *(short2v*)&d[(size_t)np * 2048 + y0 + 2 * tx] = v;
    }
  } else {
#pragma unroll
    for (int i = 0; i < 4; i++) {
      const int row = ty + 8 * i;
      short2v v = {f2bf(t[row][2 * tx]), f2bf(t[row][2 * tx + 1])};
      *(short2v*)&dd[(size_t)e * MAT_ELEMS + (size_t)(x0 + row) * 2048 + y0 + 2 * tx] = v;
    }
  }
}

// ================= 256x256 GEMM core, BK=64, 8 waves, 8-phase =================
__device__ __forceinline__ void gemm_core8(
    const short* a00, const short* a01, const short* a10, const short* a11,
    const short* __restrict__ Bb, const int T,
    short* As, short* Bs, f32x4 (&acc)[8][4])
{
  const int tid = threadIdx.x;
  const int w = tid >> 6, lane = tid & 63;
  const int wm = w >> 2, wn = w & 3;
  const int r = lane & 15, g4 = lane >> 4;
  const int l3 = lane >> 3, l7 = lane & 7;

  const size_t bOff = (size_t)(w * 16 + l3) * 2048 + (size_t)((l7 ^ l3) * 8);
  const int wdst = w * 1024;

  const unsigned aB = LDS_OFF(As), bB = LDS_OFF(Bs);
  unsigned aro[2][4], bro[2][2], csb[2];
#pragma unroll
  for (int mh = 0; mh < 2; mh++)
#pragma unroll
    for (int mq = 0; mq < 4; mq++)
      aro[mh][mq] = aB + (unsigned)(wm * 16384 + (mh * 64 + mq * 16 + r) * 128);
#pragma unroll
  for (int nh = 0; nh < 2; nh++)
#pragma unroll
    for (int nq = 0; nq < 2; nq++) {
      const int row = wn * 64 + nh * 32 + nq * 16 + r;
      bro[nh][nq] = bB + (unsigned)((row >> 7) * 16384 + (row & 127) * 128);
    }
#pragma unroll
  for (int kk = 0; kk < 2; kk++)
    csb[kk] = (unsigned)((((kk * 4 + g4) ^ (r & 7)) * 16));

#pragma unroll
  for (int i = 0; i < 8; i++)
#pragma unroll
    for (int jn = 0; jn < 4; jn++) acc[i][jn] = (f32x4){0.f, 0.f, 0.f, 0.f};

#define STG_A(tt, hh) do { \
  const short* g0_ = ((hh) ? a10 : a00) + (tt) * 64; \
  const short* g1_ = ((hh) ? a11 : a01) + (tt) * 64; \
  short* ld_ = As + ((tt) & 1) * 16384 + (hh) * 8192 + wdst; \
  GLOAD_LDS(g0_, ld_); GLOAD_LDS(g1_, ld_ + 512); \
} while (0)

#define STG_B(tt, hh) do { \
  const short* g_ = Bb + bOff + (size_t)(hh) * 128 * 2048 + (tt) * 64; \
  short* ld_ = Bs + ((tt) & 1) * 16384 + (hh) * 8192 + wdst; \
  GLOAD_LDS(g_, ld_); GLOAD_LDS(g_ + (size_t)8 * 2048, ld_ + 512); \
} while (0)

#define RD_A(mh, b32) do { \
  _Pragma("unroll") \
  for (int mq = 0; mq < 4; mq++) \
    _Pragma("unroll") \
    for (int kk = 0; kk < 2; kk++) \
      DS_READ_B128(Ar[mq * 2 + kk], aro[mh][mq] + (b32) + csb[kk]); \
} while (0)

#define RD_B(nh, DST, b32) do { \
  _Pragma("unroll") \
  for (int nq = 0; nq < 2; nq++) \
    _Pragma("unroll") \
    for (int kk = 0; kk < 2; kk++) \
      DS_READ_B128(DST[nq * 2 + kk], bro[nh][nq] + (b32) + csb[kk]); \
} while (0)

#define MM(BV, mh, nh) do { \
  __builtin_amdgcn_s_setprio(1); \
  _Pragma("unroll") \
  for (int kk = 0; kk < 2; kk++) \
    _Pragma("unroll") \
    for (int mq = 0; mq < 4; mq++) \
      _Pragma("unroll") \
      for (int nq = 0; nq < 2; nq++) \
        acc[(mh) * 4 + mq][(nh) * 2 + nq] = \
            __builtin_amdgcn_mfma_f32_16x16x32_bf16( \
                __builtin_bit_cast(bf16x8, Ar[mq * 2 + kk]), \
                __builtin_bit_cast(bf16x8, BV[nq * 2 + kk]), \
                acc[(mh) * 4 + mq][(nh) * 2 + nq], 0, 0, 0); \
  __builtin_amdgcn_s_setprio(0); \
} while (0)

  STG_B(0, 0); STG_B(0, 1);
  STG_A(0, 0); STG_A(0, 1);
  STG_B(1, 0); STG_B(1, 1);
  VMC(4);
  BAR();

  short8 Ar[8], B0[4], B1[4];

  for (int t = 0; t < T; t += 2) {
    const int t1 = t + 1;
    const int t2 = (t + 2 < T) ? t + 2 : 0;
    const int t3 = (t + 3 < T) ? t + 3 : 1;
    // P1
    RD_A(0, 0u); RD_B(0, B0, 0u);
    STG_A(t1, 0);
    BAR(); LGKM0(); MM(B0, 0, 0); BAR();
    // P2
    RD_B(1, B1, 0u);
    STG_A(t1, 1);
    BAR(); LGKM0(); MM(B1, 0, 1); BAR();
    // P3
    RD_A(1, 0u);
    STG_B(t2, 0);
    BAR(); LGKM0(); MM(B0, 1, 0); BAR();
    // P4
    STG_B(t2, 1);
    BAR(); MM(B1, 1, 1);
    VMC(4);
    BAR();
    // P5
    RD_A(0, 32768u); RD_B(0, B0, 32768u);
    STG_A(t2, 0);
    BAR(); LGKM0(); MM(B0, 0, 0); BAR();
    // P6
    RD_B(1, B1, 32768u);
    STG_A(t2, 1);
    BAR(); LGKM0(); MM(B1, 0, 1); BAR();
    // P7
    RD_A(1, 32768u);
    STG_B(t3, 0);
    BAR(); LGKM0(); MM(B0, 1, 0); BAR();
    // P8
    STG_B(t3, 1);
    BAR(); MM(B1, 1, 1);
    VMC(4);
    BAR();
  }
  VMC(0);
#undef STG_A
#undef STG_B
#undef RD_A
#undef RD_B
#undef MM
  __builtin_amdgcn_sched_barrier(0);
  asm volatile("s_nop 7\n\ts_nop 7" ::: "memory");
}

// ---------------- fused gate+up ----------------
// CONTIG=1: A from compact xg (contiguous). CONTIG=0: gathered from xb.
template<int CONTIG>
__global__ __launch_bounds__(512, 1) void fused_gu_kernel(
    const short* __restrict__ xsrc, const short* __restrict__ Bgu,
    short* __restrict__ h, const float* __restrict__ rw,
    const unsigned short* __restrict__ idx, const int* __restrict__ cnt,
    int e_param, int packed)
{
  int e, by, bx, eb;
  if (packed) {
    const int nt = cnt[16];
    const int nact = nt * 16;
    const int o = blockIdx.y * 16 + blockIdx.x;
    if (o >= nact) return;
    const int l = xcd_unmap(o, nact);
    const int tl = cnt[32 + (l >> 4)];
    e = tl >> 8; by = tl & 255; bx = l & 15; eb = e;
  } else {
    e = e_param; by = blockIdx.y; bx = blockIdx.x; eb = 0;
  }
  const int cntE = cnt[e];
  const int m0 = by * 256;
  if (m0 >= cntE) return;
  const int n0 = bx * 256;
  const unsigned short* idxe = idx + (size_t)e * BT_NUM;
  const int cm = cntE - 1;

  __shared__ short As_[32768];
  __shared__ short Bs_[32768];

  const int tid = threadIdx.x;
  const int w = tid >> 6, lane = tid & 63;
  const int l3 = lane >> 3, l7 = lane & 7;
  const size_t swz = (size_t)((l7 ^ l3) * 8);
  const short *a00, *a01, *a10, *a11;
  if (CONTIG) {
    const short* xge = xsrc + (size_t)e * BT_NUM * 2048;
    a00 = xge + (size_t)(m0 + w * 16 + l3) * 2048 + swz;
    a01 = a00 + (size_t)8 * 2048;
    a10 = a00 + (size_t)128 * 2048;
    a11 = a00 + (size_t)136 * 2048;
  } else {
    const int r0 = m0 + w * 16 + l3;
    a00 = xsrc + (size_t)idxe[min(r0, cm)] * 2048 + swz;
    a01 = xsrc + (size_t)idxe[min(r0 + 8, cm)] * 2048 + swz;
    a10 = xsrc + (size_t)idxe[min(r0 + 128, cm)] * 2048 + swz;
    a11 = xsrc + (size_t)idxe[min(r0 + 136, cm)] * 2048 + swz;
  }

  f32x4 acc[8][4];
  gemm_core8(a00, a01, a10, a11,
             Bgu + (size_t)eb * (2 * MAT_ELEMS) + (size_t)n0 * 2048,
             32, As_, Bs_, acc);

  short* he = h + (size_t)eb * BT_NUM * 2048;
  const int wm = w >> 2, wn = w & 3;
  const int rr = lane & 15, g4 = lane >> 4;
#pragma unroll
  for (int mi = 0; mi < 8; mi++) {
#pragma unroll
    for (int j = 0; j < 4; j++) {
      const int row = m0 + wm * 128 + (mi >> 2) * 64 + (mi & 3) * 16 + g4 * 4 + j;
      const int tok = idxe[min(row, cm)];
      const float wt = rw[(size_t)tok * 8 + e];
#pragma unroll
      for (int nq = 0; nq < 2; nq++) {
        const float g = acc[mi][nq][j];
        const float u = acc[mi][2 + nq][j];
        const float hv = (g / (1.f + __expf(-g))) * u * wt;
        const int c = (bx * 4 + wn) * 32 + nq * 16 + rr;
        he[(size_t)row * 2048 + c] = f2bf(hv);
      }
    }
  }
}

// ---------------- down, packed ----------------
__global__ __launch_bounds__(512, 1) void down_kernel(
    const short* __restrict__ h, const short* __restrict__ WdT,
    short* __restrict__ dout, const int* __restrict__ cnt)
{
  const int nt = cnt[16];
  const int nact = nt * 8;
  const int o = blockIdx.y * 8 + blockIdx.x;
  if (o >= nact) return;
  const int l = xcd_unmap(o, nact);
  const int tl = cnt[32 + (l >> 3)];
  const int e = tl >> 8, by = tl & 255, bx = l & 7;
  const int cntE = cnt[e];
  const int m0 = by * 256;
  if (m0 >= cntE) return;
  const int n0 = bx * 256;

  __shared__ short As_[32768];
  __shared__ short Bs_[32768];

  const int tid = threadIdx.x;
  const int w = tid >> 6, lane = tid & 63;
  const int l3 = lane >> 3, l7 = lane & 7;
  const size_t swz = (size_t)((l7 ^ l3) * 8);
  const short* he = h + (size_t)e * BT_NUM * 2048;
  const short* a00 = he + (size_t)(m0 + w * 16 + l3) * 2048 + swz;
  const short* a01 = a00 + (size_t)8 * 2048;
  const short* a10 = a00 + (size_t)128 * 2048;
  const short* a11 = a00 + (size_t)136 * 2048;

  f32x4 acc[8][4];
  gemm_core8(a00, a01, a10, a11,
             WdT + (size_t)e * MAT_ELEMS + (size_t)n0 * 2048,
             32, As_, Bs_, acc);

  short* de = dout + (size_t)e * BT_NUM * 2048;
  const int wm = w >> 2, wn = w & 3;
  const int rr = lane & 15, g4 = lane >> 4;
#pragma unroll
  for (int mi = 0; mi < 8; mi++) {
#pragma unroll
    for (int ni = 0; ni < 4; ni++) {
      const int col = n0 + wn * 64 + (ni >> 1) * 32 + (ni & 1) * 16 + rr;
#pragma unroll
      for (int j = 0; j < 4; j++) {
        const int row = m0 + wm * 128 + (mi >> 2) * 64 + (mi & 3) * 16 + g4 * 4 + j;
        de[(size_t)row * 2048 + col] = f2bf(acc[mi][ni][j]);
      }
    }
  }
}

// ---------------- down, fallback: atomic scatter-add ----------------
__global__ __launch_bounds__(512, 1) void down_atomic_kernel(
    const short* __restrict__ h, const short* __restrict__ WdT,
    float* __restrict__ out,
    const unsigned short* __restrict__ idx, const int* __restrict__ cnt,
    int e_param)
{
  const int e = e_param;
  const int cntE = cnt[e];
  const int by = blockIdx.y, bx = blockIdx.x;
  const int m0 = by * 256;
  if (m0 >= cntE) return;
  const int n0 = bx * 256;
  const unsigned short* idxe = idx + (size_t)e * BT_NUM;

  __shared__ short As_[32768];
  __shared__ short Bs_[32768];

  const int tid = threadIdx.x;
  const int w = tid >> 6, lane = tid & 63;
  const int l3 = lane >> 3, l7 = lane & 7;
  const size_t swz = (size_t)((l7 ^ l3) * 8);
  const short* a00 = h + (size_t)(m0 + w * 16 + l3) * 2048 + swz;
  const short* a01 = a00 + (size_t)8 * 2048;
  const short* a10 = a00 + (size_t)128 * 2048;
  const short* a11 = a00 + (size_t)136 * 2048;

  f32x4 acc[8][4];
  gemm_core8(a00, a01, a10, a11, WdT + (size_t)n0 * 2048, 32, As_, Bs_, acc);

  const int wm = w >> 2, wn = w & 3;
  const int rr = lane & 15, g4 = lane >> 4;
#pragma unroll
  for (int mi = 0; mi < 8; mi++) {
#pragma unroll
    for (int ni = 0; ni < 4; ni++) {
      const int col = n0 + wn * 64 + (ni >> 1) * 32 + (ni & 1) * 16 + rr;
#pragma unroll
      for (int j = 0; j < 4; j++) {
        const int row = m0 + wm * 128 + (mi >> 2) * 64 + (mi & 3) * 16 + g4 * 4 + j;
        if (row < cntE) {
          const int tok = idxe[row];
          unsafeAtomicAdd(&out[(size_t)tok * 2048 + col], acc[mi][ni][j]);
        }
      }
    }
  }
}

// ---------------- combine ----------------
__global__ __launch_bounds__(256) void combine_kernel(
    const short* __restrict__ dout, const unsigned short* __restrict__ inv,
    const unsigned char* __restrict__ invn, float* __restrict__ out)
{
  const int t = blockIdx.x;
  const int nv = invn[t];
  const int c = threadIdx.x * 8;
  float s[8];
#pragma unroll
  for (int j = 0; j < 8; j++) s[j] = 0.f;
  for (int v = 0; v < nv; v++) {
    const unsigned entry = inv[(size_t)t * E_NUM + v];
    const size_t rowoff = ((size_t)(entry >> 12) * BT_NUM + (entry & 4095)) * 2048;
    const short8 d8 = *(const short8*)&dout[rowoff + c];
#pragma unroll
    for (int j = 0; j < 8; j++) s[j] += bf2f(d8[j]);
  }
  float* op = out + (size_t)t * 2048 + c;
  *(f32x4*)op = (f32x4){s[0], s[1], s[2], s[3]};
  *(f32x4*)(op + 4) = (f32x4){s[4], s[5], s[6], s[7]};
}

extern "C" void kernel_launch(void* const* d_in, const int* in_sizes, int n_in,
                              void* d_out, int out_size, void* d_ws, size_t ws_size,
                              hipStream_t stream)
{
  const float* x  = (const float*)d_in[0];
  const float* Wg = (const float*)d_in[1];
  const float* Wu = (const float*)d_in[2];
  const float* Wd = (const float*)d_in[3];
  const float* Wr = (const float*)d_in[4];
  const float* tp = (const float*)d_in[5];
  float* out = (float*)d_out;

  char* ws = (char*)d_ws;
  const size_t SZ_RW   = 131072;
  const size_t SZ_CNT  = 4096;
  const size_t SZ_IDX  = (size_t)E_NUM * BT_NUM * 2;
  const size_t SZ_INV  = (size_t)BT_NUM * E_NUM * 2;
  const size_t SZ_INVN = 8192;
  const size_t SZ_XB   = (size_t)BT_NUM * 2048 * 2;            // 16 MiB
  const size_t SZ_XG   = (size_t)E_NUM * BT_NUM * 2048 * 2;    // 128 MiB
  const size_t SZ_BGU_E = 2 * MAT_ELEMS * 2;
  const size_t SZ_WDT_E = MAT_ELEMS * 2;
  const size_t SZ_H_E  = (size_t)BT_NUM * 2048 * 2;

  const size_t HEAD = SZ_RW + SZ_CNT + SZ_IDX + SZ_INV + SZ_INVN;
  const size_t FULL    = HEAD + SZ_XB + 8 * SZ_BGU_E + 8 * SZ_WDT_E + 8 * SZ_H_E;
  const size_t FULL_XG = HEAD + SZ_XG + 8 * SZ_BGU_E + 8 * SZ_WDT_E + 8 * SZ_H_E;

  float* rw = (float*)ws;
  int* cnt = (int*)(ws + SZ_RW);
  unsigned short* idx = (unsigned short*)(ws + SZ_RW + SZ_CNT);
  unsigned short* inv = (unsigned short*)(ws + SZ_RW + SZ_CNT + SZ_IDX);
  unsigned char* invn = (unsigned char*)(ws + SZ_RW + SZ_CNT + SZ_IDX + SZ_INV);

  router_kernel<<<BT_NUM, 256, 0, stream>>>(x, Wr, tp, rw);
  init_cnt_kernel<<<1, 64, 0, stream>>>(cnt);
  build_idx_kernel<<<16, 256, 0, stream>>>(rw, cnt, idx, inv, invn);
  pack_tiles_kernel<<<1, 64, 0, stream>>>(cnt);

  if (ws_size >= FULL_XG) {
    short* xg  = (short*)(ws + HEAD);
    char* rest = ws + HEAD + SZ_XG;
    short* Bgu = (short*)rest;
    short* WdT = (short*)(rest + 8 * SZ_BGU_E);
    short* h   = (short*)(rest + 8 * SZ_BGU_E + 8 * SZ_WDT_E);
    short* dout = Bgu;   // alias: Bgu dead after fused_gu

    gather_x_kernel<<<MAXT, 256, 0, stream>>>(x, idx, cnt, xg);
    transpose_cvt_kernel<<<dim3(64, 32, 24), dim3(32, 8), 0, stream>>>(
        Wg, Wu, Wd, Bgu, WdT, 8);
    fused_gu_kernel<1><<<dim3(16, MAXT), 512, 0, stream>>>(
        xg, Bgu, h, rw, idx, cnt, 0, 1);
    down_kernel<<<dim3(8, MAXT), 512, 0, stream>>>(h, WdT, dout, cnt);
    combine_kernel<<<BT_NUM, 256, 0, stream>>>(dout, inv, invn, out);
  } else if (ws_size >= FULL) {
    short* xb  = (short*)(ws + HEAD);
    char* rest = ws + HEAD + SZ_XB;
    short* Bgu = (short*)rest;
    short* WdT = (short*)(rest + 8 * SZ_BGU_E);
    short* h   = (short*)(rest + 8 * SZ_BGU_E + 8 * SZ_WDT_E);
    short* dout = Bgu;

    cvt_x_kernel<<<4096, 256, 0, stream>>>(x, xb);
    transpose_cvt_kernel<<<dim3(64, 32, 24), dim3(32, 8), 0, stream>>>(
        Wg, Wu, Wd, Bgu, WdT, 8);
    fused_gu_kernel<0><<<dim3(16, MAXT), 512, 0, stream>>>(
        xb, Bgu, h, rw, idx, cnt, 0, 1);
    down_kernel<<<dim3(8, MAXT), 512, 0, stream>>>(h, WdT, dout, cnt);
    combine_kernel<<<BT_NUM, 256, 0, stream>>>(dout, inv, invn, out);
  } else {
    short* xb  = (short*)(ws + HEAD);
    char* rest = ws + HEAD + SZ_XB;
    short* Bgu = (short*)rest;
    short* WdT = (short*)(rest + SZ_BGU_E);
    short* h   = (short*)(rest + SZ_BGU_E + SZ_WDT_E);

    cvt_x_kernel<<<4096, 256, 0, stream>>>(x, xb);
    zero_out_kernel<<<8192, 256, 0, stream>>>(out);
    for (int e = 0; e < 8; e++) {
      transpose_cvt_kernel<<<dim3(64, 32, 3), dim3(32, 8), 0, stream>>>(
          Wg + (size_t)e * MAT_ELEMS, Wu + (size_t)e * MAT_ELEMS,
          Wd + (size_t)e * MAT_ELEMS, Bgu, WdT, 1);
      fused_gu_kernel<0><<<dim3(16, 16), 512, 0, stream>>>(
          xb, Bgu, h, rw, idx, cnt, e, 0);
      down_atomic_kernel<<<dim3(8, 16), 512, 0, stream>>>(
          h, WdT, out, idx, cnt, e);
    }
  }
}

// Round 12
// 602.086 us; speedup vs baseline: 1.0426x; 1.0426x over previous
//
#include <hip/hip_runtime.h>
#include <hip/hip_bf16.h>
#include <math.h>

// GoldenMoE: B=2,T=2048,D=2048,E=8,F=2048.
// Round 12: r11 with gather_x parallelized (8x136 blocks, 32 rows each).
// All GEMM/down/transpose/combine paths byte-identical to r11.

#define E_NUM 8
#define BT_NUM 4096
#define MAT_ELEMS ((size_t)2048 * 2048)
#define MAXT 136

typedef short short8 __attribute__((ext_vector_type(8)));
typedef short short2v __attribute__((ext_vector_type(2)));
typedef float f32x4 __attribute__((ext_vector_type(4)));
typedef __bf16 bf16x8 __attribute__((ext_vector_type(8)));

__device__ __forceinline__ short f2bf(float f) {
  __hip_bfloat16 h = __float2bfloat16(f);
  return __builtin_bit_cast(short, h);
}
__device__ __forceinline__ float bf2f(short s) {
  __hip_bfloat16 h = __builtin_bit_cast(__hip_bfloat16, s);
  return __bfloat162float(h);
}

#define GLOAD_LDS(gptr, lptr) \
  __builtin_amdgcn_global_load_lds( \
      (const __attribute__((address_space(1))) unsigned int*)(gptr), \
      (__attribute__((address_space(3))) unsigned int*)(lptr), 16, 0, 0)

#define LDS_OFF(p) ((unsigned)(size_t)(__attribute__((address_space(3))) const short*)(p))

#define DS_READ_B128(d, a) \
  asm volatile("ds_read_b128 %0, %1" : "=v"(d) : "v"(a))

#define BAR() __builtin_amdgcn_s_barrier()
#define LGKM0() do { \
  asm volatile("s_waitcnt lgkmcnt(0)" ::: "memory"); \
  __builtin_amdgcn_sched_barrier(0); \
} while (0)
#define VMC(n) asm volatile("s_waitcnt vmcnt(" #n ")" ::: "memory")

// XCD-bijective unmap
__device__ __forceinline__ int xcd_unmap(int o, int nact) {
  const int q = nact >> 3, rr = nact & 7;
  const int xcd = o & 7, seq = o >> 3;
  return (xcd < rr) ? xcd * (q + 1) + seq
                    : rr * (q + 1) + (xcd - rr) * q + seq;
}

// ---------------- router ----------------
__global__ __launch_bounds__(256) void router_kernel(
    const float* __restrict__ x, const float* __restrict__ Wr,
    const float* __restrict__ temp, float* __restrict__ rw)
{
  const int bt = blockIdx.x;
  const int tid = threadIdx.x;
  const float* xp = x + (size_t)bt * 2048;
  float acc[E_NUM];
#pragma unroll
  for (int e = 0; e < E_NUM; e++) acc[e] = 0.f;
  for (int d = tid; d < 2048; d += 256) {
    float xv = xp[d];
    const float* wr = Wr + (size_t)d * E_NUM;
#pragma unroll
    for (int e = 0; e < E_NUM; e++) acc[e] += xv * wr[e];
  }
#pragma unroll
  for (int e = 0; e < E_NUM; e++) {
    float v = acc[e];
#pragma unroll
    for (int off = 32; off > 0; off >>= 1) v += __shfl_down(v, off, 64);
    acc[e] = v;
  }
  __shared__ float part[4][E_NUM];
  const int wid = tid >> 6, lane = tid & 63;
  if (lane == 0) {
#pragma unroll
    for (int e = 0; e < E_NUM; e++) part[wid][e] = acc[e];
  }
  __syncthreads();
  if (tid == 0) {
    const float t = temp[0];
    float wz[E_NUM], fb[E_NUM];
    float wsum = 0.f;
#pragma unroll
    for (int e = 0; e < E_NUM; e++) {
      float l = part[0][e] + part[1][e] + part[2][e] + part[3][e];
      float ih = 1.f / (1.f + expf(-l / t));
      float ds = fabsf(ih - 0.36787944117144233f);
      float in_zone = (ih >= 0.21231792754821915f && ih <= 0.5f) ? 1.f : 0.f;
      wz[e] = expf(-ds / 0.1f) * in_zone;
      wsum += wz[e];
      fb[e] = expf(-ds / 0.3f);
    }
    float w[E_NUM];
    if (wsum < 1e-8f) {
      int i1 = 0;
#pragma unroll
      for (int e = 1; e < E_NUM; e++) if (fb[e] > fb[i1]) i1 = e;
      int i2 = -1;
#pragma unroll
      for (int e = 0; e < E_NUM; e++) if (e != i1 && (i2 < 0 || fb[e] > fb[i2])) i2 = e;
      float s = fmaxf(fb[i1] + fb[i2], 1e-8f);
#pragma unroll
      for (int e = 0; e < E_NUM; e++) w[e] = (e == i1 || e == i2) ? fb[e] / s : 0.f;
    } else {
#pragma unroll
      for (int e = 0; e < E_NUM; e++) w[e] = wz[e];
    }
    float s2 = 0.f;
#pragma unroll
    for (int e = 0; e < E_NUM; e++) s2 += w[e];
    s2 = fmaxf(s2, 1e-8f);
    float inv = 1.f / s2;
#pragma unroll
    for (int e = 0; e < E_NUM; e++) rw[(size_t)bt * E_NUM + e] = w[e] * inv;
  }
}

// ---------------- sparse bookkeeping ----------------
__global__ void init_cnt_kernel(int* __restrict__ cnt) {
  if (threadIdx.x < 32) cnt[threadIdx.x] = 0;
}

__global__ __launch_bounds__(256) void build_idx_kernel(
    const float* __restrict__ rw, int* __restrict__ cnt,
    unsigned short* __restrict__ idx,
    unsigned short* __restrict__ inv, unsigned char* __restrict__ invn)
{
  const int t = blockIdx.x * 256 + threadIdx.x;
  const float* w = rw + (size_t)t * E_NUM;
  int s = 0;
#pragma unroll
  for (int e = 0; e < E_NUM; e++) {
    if (w[e] != 0.f) {
      int p = atomicAdd(&cnt[e], 1);
      idx[(size_t)e * BT_NUM + p] = (unsigned short)t;
      inv[(size_t)t * E_NUM + s] = (unsigned short)((e << 12) | p);
      s++;
    }
  }
  invn[t] = (unsigned char)s;
}

__global__ void pack_tiles_kernel(int* __restrict__ cnt) {
  if (threadIdx.x == 0) {
    int n = 0;
    for (int e = 0; e < E_NUM; e++) {
      const int nt = (cnt[e] + 255) >> 8;
      for (int by = 0; by < nt; by++) cnt[32 + n++] = (e << 8) | by;
    }
    cnt[16] = n;
  }
}

__global__ __launch_bounds__(256) void zero_out_kernel(float* __restrict__ out) {
  const size_t i = ((size_t)blockIdx.x * 256 + threadIdx.x) * 4;
  *(f32x4*)(out + i) = (f32x4){0.f, 0.f, 0.f, 0.f};
}

// ---------------- x f32 -> bf16 (dense, non-XG paths) ----------------
__global__ __launch_bounds__(256) void cvt_x_kernel(
    const float* __restrict__ x, short* __restrict__ xb)
{
  const size_t base = ((size_t)blockIdx.x * 256 + threadIdx.x) * 8;
  f32x4 v0 = *(const f32x4*)(x + base);
  f32x4 v1 = *(const f32x4*)(x + base + 4);
  short8 p;
#pragma unroll
  for (int j = 0; j < 4; j++) { p[j] = f2bf(v0[j]); p[4 + j] = f2bf(v1[j]); }
  *(short8*)(xb + base) = p;
}

// ---------------- gather x -> compact per-expert xg (bf16), PARALLEL ----------------
// grid (8 chunks, MAXT tiles), 256 threads; each block: 32 rows x 2048 cols.
__global__ __launch_bounds__(256) void gather_x_kernel(
    const float* __restrict__ x, const unsigned short* __restrict__ idx,
    const int* __restrict__ cnt, short* __restrict__ xg)
{
  const int nt = cnt[16];
  if ((int)blockIdx.y >= nt) return;
  const int tl = cnt[32 + blockIdx.y];
  const int e = tl >> 8, by = tl & 255;
  const int cntE = cnt[e];
  const int m0 = by * 256 + blockIdx.x * 32;
  const int cm = cntE - 1;
  const unsigned short* idxe = idx + (size_t)e * BT_NUM;
  short* xge = xg + (size_t)e * BT_NUM * 2048;
  const int c = threadIdx.x * 8;
#pragma unroll 4
  for (int rloc = 0; rloc < 32; rloc++) {
    const int row = m0 + rloc;
    const int tok = idxe[min(row, cm)];
    const float* sp = x + (size_t)tok * 2048 + c;
    f32x4 v0 = *(const f32x4*)sp;
    f32x4 v1 = *(const f32x4*)(sp + 4);
    short8 p;
#pragma unroll
    for (int j = 0; j < 4; j++) { p[j] = f2bf(v0[j]); p[4 + j] = f2bf(v1[j]); }
    *(short8*)&xge[(size_t)row * 2048 + c] = p;
  }
}

// ------------- transpose + f32->bf16 (64x32 tile, short2 writes) -------------
__global__ __launch_bounds__(256) void transpose_cvt_kernel(
    const float* __restrict__ sg, const float* __restrict__ su, const float* __restrict__ sd,
    short* __restrict__ dgu, short* __restrict__ dd, int nexp)
{
  const int which = blockIdx.z / nexp, e = blockIdx.z % nexp;
  __shared__ float t[32][65];
  const int tx = threadIdx.x, ty = threadIdx.y;
  const int x0 = blockIdx.x * 32, y0 = blockIdx.y * 64;
  const float* s = (which == 0 ? sg : which == 1 ? su : sd) + (size_t)e * MAT_ELEMS;
#pragma unroll
  for (int i = 0; i < 8; i++)
    t[tx][ty + 8 * i] = s[(size_t)(y0 + ty + 8 * i) * 2048 + x0 + tx];
  __syncthreads();
  if (which < 2) {
    short* d = dgu + (size_t)e * (2 * MAT_ELEMS);
#pragma unroll
    for (int i = 0; i < 4; i++) {
      const int row = ty + 8 * i;
      const int col = x0 + row;
      const int np = ((col >> 5) * 64) + which * 32 + (col & 31);
      short2v v = {f2bf(t[row][2 * tx]), f2bf(t[row][2 * tx + 1])};
      *(short2v*)&d[(size_t)np * 2048 + y0 + 2 * tx] = v;
    }
  } else {
#pragma unroll
    for (int i = 0; i < 4; i++) {
      const int row = ty + 8 * i;
      short2v v = {f2bf(t[row][2 * tx]), f2bf(t[row][2 * tx + 1])};
      *(short2v*)&dd[(size_t)e * MAT_ELEMS + (size_t)(x0 + row) * 2048 + y0 + 2 * tx] = v;
    }
  }
}

// ================= 256x256 GEMM core, BK=64, 8 waves, 8-phase =================
__device__ __forceinline__ void gemm_core8(
    const short* a00, const short* a01, const short* a10, const short* a11,
    const short* __restrict__ Bb, const int T,
    short* As, short* Bs, f32x4 (&acc)[8][4])
{
  const int tid = threadIdx.x;
  const int w = tid >> 6, lane = tid & 63;
  const int wm = w >> 2, wn = w & 3;
  const int r = lane & 15, g4 = lane >> 4;
  const int l3 = lane >> 3, l7 = lane & 7;

  const size_t bOff = (size_t)(w * 16 + l3) * 2048 + (size_t)((l7 ^ l3) * 8);
  const int wdst = w * 1024;

  const unsigned aB = LDS_OFF(As), bB = LDS_OFF(Bs);
  unsigned aro[2][4], bro[2][2], csb[2];
#pragma unroll
  for (int mh = 0; mh < 2; mh++)
#pragma unroll
    for (int mq = 0; mq < 4; mq++)
      aro[mh][mq] = aB + (unsigned)(wm * 16384 + (mh * 64 + mq * 16 + r) * 128);
#pragma unroll
  for (int nh = 0; nh < 2; nh++)
#pragma unroll
    for (int nq = 0; nq < 2; nq++) {
      const int row = wn * 64 + nh * 32 + nq * 16 + r;
      bro[nh][nq] = bB + (unsigned)((row >> 7) * 16384 + (row & 127) * 128);
    }
#pragma unroll
  for (int kk = 0; kk < 2; kk++)
    csb[kk] = (unsigned)((((kk * 4 + g4) ^ (r & 7)) * 16));

#pragma unroll
  for (int i = 0; i < 8; i++)
#pragma unroll
    for (int jn = 0; jn < 4; jn++) acc[i][jn] = (f32x4){0.f, 0.f, 0.f, 0.f};

#define STG_A(tt, hh) do { \
  const short* g0_ = ((hh) ? a10 : a00) + (tt) * 64; \
  const short* g1_ = ((hh) ? a11 : a01) + (tt) * 64; \
  short* ld_ = As + ((tt) & 1) * 16384 + (hh) * 8192 + wdst; \
  GLOAD_LDS(g0_, ld_); GLOAD_LDS(g1_, ld_ + 512); \
} while (0)

#define STG_B(tt, hh) do { \
  const short* g_ = Bb + bOff + (size_t)(hh) * 128 * 2048 + (tt) * 64; \
  short* ld_ = Bs + ((tt) & 1) * 16384 + (hh) * 8192 + wdst; \
  GLOAD_LDS(g_, ld_); GLOAD_LDS(g_ + (size_t)8 * 2048, ld_ + 512); \
} while (0)

#define RD_A(mh, b32) do { \
  _Pragma("unroll") \
  for (int mq = 0; mq < 4; mq++) \
    _Pragma("unroll") \
    for (int kk = 0; kk < 2; kk++) \
      DS_READ_B128(Ar[mq * 2 + kk], aro[mh][mq] + (b32) + csb[kk]); \
} while (0)

#define RD_B(nh, DST, b32) do { \
  _Pragma("unroll") \
  for (int nq = 0; nq < 2; nq++) \
    _Pragma("unroll") \
    for (int kk = 0; kk < 2; kk++) \
      DS_READ_B128(DST[nq * 2 + kk], bro[nh][nq] + (b32) + csb[kk]); \
} while (0)

#define MM(BV, mh, nh) do { \
  __builtin_amdgcn_s_setprio(1); \
  _Pragma("unroll") \
  for (int kk = 0; kk < 2; kk++) \
    _Pragma("unroll") \
    for (int mq = 0; mq < 4; mq++) \
      _Pragma("unroll") \
      for (int nq = 0; nq < 2; nq++) \
        acc[(mh) * 4 + mq][(nh) * 2 + nq] = \
            __builtin_amdgcn_mfma_f32_16x16x32_bf16( \
                __builtin_bit_cast(bf16x8, Ar[mq * 2 + kk]), \
                __builtin_bit_cast(bf16x8, BV[nq * 2 + kk]), \
                acc[(mh) * 4 + mq][(nh) * 2 + nq], 0, 0, 0); \
  __builtin_amdgcn_s_setprio(0); \
} while (0)

  STG_B(0, 0); STG_B(0, 1);
  STG_A(0, 0); STG_A(0, 1);
  STG_B(1, 0); STG_B(1, 1);
  VMC(4);
  BAR();

  short8 Ar[8], B0[4], B1[4];

  for (int t = 0; t < T; t += 2) {
    const int t1 = t + 1;
    const int t2 = (t + 2 < T) ? t + 2 : 0;
    const int t3 = (t + 3 < T) ? t + 3 : 1;
    // P1
    RD_A(0, 0u); RD_B(0, B0, 0u);
    STG_A(t1, 0);
    BAR(); LGKM0(); MM(B0, 0, 0); BAR();
    // P2
    RD_B(1, B1, 0u);
    STG_A(t1, 1);
    BAR(); LGKM0(); MM(B1, 0, 1); BAR();
    // P3
    RD_A(1, 0u);
    STG_B(t2, 0);
    BAR(); LGKM0(); MM(B0, 1, 0); BAR();
    // P4
    STG_B(t2, 1);
    BAR(); MM(B1, 1, 1);
    VMC(4);
    BAR();
    // P5
    RD_A(0, 32768u); RD_B(0, B0, 32768u);
    STG_A(t2, 0);
    BAR(); LGKM0(); MM(B0, 0, 0); BAR();
    // P6
    RD_B(1, B1, 32768u);
    STG_A(t2, 1);
    BAR(); LGKM0(); MM(B1, 0, 1); BAR();
    // P7
    RD_A(1, 32768u);
    STG_B(t3, 0);
    BAR(); LGKM0(); MM(B0, 1, 0); BAR();
    // P8
    STG_B(t3, 1);
    BAR(); MM(B1, 1, 1);
    VMC(4);
    BAR();
  }
  VMC(0);
#undef STG_A
#undef STG_B
#undef RD_A
#undef RD_B
#undef MM
  __builtin_amdgcn_sched_barrier(0);
  asm volatile("s_nop 7\n\ts_nop 7" ::: "memory");
}

// ---------------- fused gate+up ----------------
template<int CONTIG>
__global__ __launch_bounds__(512, 1) void fused_gu_kernel(
    const short* __restrict__ xsrc, const short* __restrict__ Bgu,
    short* __restrict__ h, const float* __restrict__ rw,
    const unsigned short* __restrict__ idx, const int* __restrict__ cnt,
    int e_param, int packed)
{
  int e, by, bx, eb;
  if (packed) {
    const int nt = cnt[16];
    const int nact = nt * 16;
    const int o = blockIdx.y * 16 + blockIdx.x;
    if (o >= nact) return;
    const int l = xcd_unmap(o, nact);
    const int tl = cnt[32 + (l >> 4)];
    e = tl >> 8; by = tl & 255; bx = l & 15; eb = e;
  } else {
    e = e_param; by = blockIdx.y; bx = blockIdx.x; eb = 0;
  }
  const int cntE = cnt[e];
  const int m0 = by * 256;
  if (m0 >= cntE) return;
  const int n0 = bx * 256;
  const unsigned short* idxe = idx + (size_t)e * BT_NUM;
  const int cm = cntE - 1;

  __shared__ short As_[32768];
  __shared__ short Bs_[32768];

  const int tid = threadIdx.x;
  const int w = tid >> 6, lane = tid & 63;
  const int l3 = lane >> 3, l7 = lane & 7;
  const size_t swz = (size_t)((l7 ^ l3) * 8);
  const short *a00, *a01, *a10, *a11;
  if (CONTIG) {
    const short* xge = xsrc + (size_t)e * BT_NUM * 2048;
    a00 = xge + (size_t)(m0 + w * 16 + l3) * 2048 + swz;
    a01 = a00 + (size_t)8 * 2048;
    a10 = a00 + (size_t)128 * 2048;
    a11 = a00 + (size_t)136 * 2048;
  } else {
    const int r0 = m0 + w * 16 + l3;
    a00 = xsrc + (size_t)idxe[min(r0, cm)] * 2048 + swz;
    a01 = xsrc + (size_t)idxe[min(r0 + 8, cm)] * 2048 + swz;
    a10 = xsrc + (size_t)idxe[min(r0 + 128, cm)] * 2048 + swz;
    a11 = xsrc + (size_t)idxe[min(r0 + 136, cm)] * 2048 + swz;
  }

  f32x4 acc[8][4];
  gemm_core8(a00, a01, a10, a11,
             Bgu + (size_t)eb * (2 * MAT_ELEMS) + (size_t)n0 * 2048,
             32, As_, Bs_, acc);

  short* he = h + (size_t)eb * BT_NUM * 2048;
  const int wm = w >> 2, wn = w & 3;
  const int rr = lane & 15, g4 = lane >> 4;
#pragma unroll
  for (int mi = 0; mi < 8; mi++) {
#pragma unroll
    for (int j = 0; j < 4; j++) {
      const int row = m0 + wm * 128 + (mi >> 2) * 64 + (mi & 3) * 16 + g4 * 4 + j;
      const int tok = idxe[min(row, cm)];
      const float wt = rw[(size_t)tok * 8 + e];
#pragma unroll
      for (int nq = 0; nq < 2; nq++) {
        const float g = acc[mi][nq][j];
        const float u = acc[mi][2 + nq][j];
        const float hv = (g / (1.f + __expf(-g))) * u * wt;
        const int c = (bx * 4 + wn) * 32 + nq * 16 + rr;
        he[(size_t)row * 2048 + c] = f2bf(hv);
      }
    }
  }
}

// ---------------- down, packed ----------------
__global__ __launch_bounds__(512, 1) void down_kernel(
    const short* __restrict__ h, const short* __restrict__ WdT,
    short* __restrict__ dout, const int* __restrict__ cnt)
{
  const int nt = cnt[16];
  const int nact = nt * 8;
  const int o = blockIdx.y * 8 + blockIdx.x;
  if (o >= nact) return;
  const int l = xcd_unmap(o, nact);
  const int tl = cnt[32 + (l >> 3)];
  const int e = tl >> 8, by = tl & 255, bx = l & 7;
  const int cntE = cnt[e];
  const int m0 = by * 256;
  if (m0 >= cntE) return;
  const int n0 = bx * 256;

  __shared__ short As_[32768];
  __shared__ short Bs_[32768];

  const int tid = threadIdx.x;
  const int w = tid >> 6, lane = tid & 63;
  const int l3 = lane >> 3, l7 = lane & 7;
  const size_t swz = (size_t)((l7 ^ l3) * 8);
  const short* he = h + (size_t)e * BT_NUM * 2048;
  const short* a00 = he + (size_t)(m0 + w * 16 + l3) * 2048 + swz;
  const short* a01 = a00 + (size_t)8 * 2048;
  const short* a10 = a00 + (size_t)128 * 2048;
  const short* a11 = a00 + (size_t)136 * 2048;

  f32x4 acc[8][4];
  gemm_core8(a00, a01, a10, a11,
             WdT + (size_t)e * MAT_ELEMS + (size_t)n0 * 2048,
             32, As_, Bs_, acc);

  short* de = dout + (size_t)e * BT_NUM * 2048;
  const int wm = w >> 2, wn = w & 3;
  const int rr = lane & 15, g4 = lane >> 4;
#pragma unroll
  for (int mi = 0; mi < 8; mi++) {
#pragma unroll
    for (int ni = 0; ni < 4; ni++) {
      const int col = n0 + wn * 64 + (ni >> 1) * 32 + (ni & 1) * 16 + rr;
#pragma unroll
      for (int j = 0; j < 4; j++) {
        const int row = m0 + wm * 128 + (mi >> 2) * 64 + (mi & 3) * 16 + g4 * 4 + j;
        de[(size_t)row * 2048 + col] = f2bf(acc[mi][ni][j]);
      }
    }
  }
}

// ---------------- down, fallback: atomic scatter-add ----------------
__global__ __launch_bounds__(512, 1) void down_atomic_kernel(
    const short* __restrict__ h, const short* __restrict__ WdT,
    float* __restrict__ out,
    const unsigned short* __restrict__ idx, const int* __restrict__ cnt,
    int e_param)
{
  const int e = e_param;
  const int cntE = cnt[e];
  const int by = blockIdx.y, bx = blockIdx.x;
  const int m0 = by * 256;
  if (m0 >= cntE) return;
  const int n0 = bx * 256;
  const unsigned short* idxe = idx + (size_t)e * BT_NUM;

  __shared__ short As_[32768];
  __shared__ short Bs_[32768];

  const int tid = threadIdx.x;
  const int w = tid >> 6, lane = tid & 63;
  const int l3 = lane >> 3, l7 = lane & 7;
  const size_t swz = (size_t)((l7 ^ l3) * 8);
  const short* a00 = h + (size_t)(m0 + w * 16 + l3) * 2048 + swz;
  const short* a01 = a00 + (size_t)8 * 2048;
  const short* a10 = a00 + (size_t)128 * 2048;
  const short* a11 = a00 + (size_t)136 * 2048;

  f32x4 acc[8][4];
  gemm_core8(a00, a01, a10, a11, WdT + (size_t)n0 * 2048, 32, As_, Bs_, acc);

  const int wm = w >> 2, wn = w & 3;
  const int rr = lane & 15, g4 = lane >> 4;
#pragma unroll
  for (int mi = 0; mi < 8; mi++) {
#pragma unroll
    for (int ni = 0; ni < 4; ni++) {
      const int col = n0 + wn * 64 + (ni >> 1) * 32 + (ni & 1) * 16 + rr;
#pragma unroll
      for (int j = 0; j < 4; j++) {
        const int row = m0 + wm * 128 + (mi >> 2) * 64 + (mi & 3) * 16 + g4 * 4 + j;
        if (row < cntE) {
          const int tok = idxe[row];
          unsafeAtomicAdd(&out[(size_t)tok * 2048 + col], acc[mi][ni][j]);
        }
      }
    }
  }
}

// ---------------- combine ----------------
__global__ __launch_bounds__(256) void combine_kernel(
    const short* __restrict__ dout, const unsigned short* __restrict__ inv,
    const unsigned char* __restrict__ invn, float* __restrict__ out)
{
  const int t = blockIdx.x;
  const int nv = invn[t];
  const int c = threadIdx.x * 8;
  float s[8];
#pragma unroll
  for (int j = 0; j < 8; j++) s[j] = 0.f;
  for (int v = 0; v < nv; v++) {
    const unsigned entry = inv[(size_t)t * E_NUM + v];
    const size_t rowoff = ((size_t)(entry >> 12) * BT_NUM + (entry & 4095)) * 2048;
    const short8 d8 = *(const short8*)&dout[rowoff + c];
#pragma unroll
    for (int j = 0; j < 8; j++) s[j] += bf2f(d8[j]);
  }
  float* op = out + (size_t)t * 2048 + c;
  *(f32x4*)op = (f32x4){s[0], s[1], s[2], s[3]};
  *(f32x4*)(op + 4) = (f32x4){s[4], s[5], s[6], s[7]};
}

extern "C" void kernel_launch(void* const* d_in, const int* in_sizes, int n_in,
                              void* d_out, int out_size, void* d_ws, size_t ws_size,
                              hipStream_t stream)
{
  const float* x  = (const float*)d_in[0];
  const float* Wg = (const float*)d_in[1];
  const float* Wu = (const float*)d_in[2];
  const float* Wd = (const float*)d_in[3];
  const float* Wr = (const float*)d_in[4];
  const float* tp = (const float*)d_in[5];
  float* out = (float*)d_out;

  char* ws = (char*)d_ws;
  const size_t SZ_RW   = 131072;
  const size_t SZ_CNT  = 4096;
  const size_t SZ_IDX  = (size_t)E_NUM * BT_NUM * 2;
  const size_t SZ_INV  = (size_t)BT_NUM * E_NUM * 2;
  const size_t SZ_INVN = 8192;
  const size_t SZ_XB   = (size_t)BT_NUM * 2048 * 2;
  const size_t SZ_XG   = (size_t)E_NUM * BT_NUM * 2048 * 2;
  const size_t SZ_BGU_E = 2 * MAT_ELEMS * 2;
  const size_t SZ_WDT_E = MAT_ELEMS * 2;
  const size_t SZ_H_E  = (size_t)BT_NUM * 2048 * 2;

  const size_t HEAD = SZ_RW + SZ_CNT + SZ_IDX + SZ_INV + SZ_INVN;
  const size_t FULL    = HEAD + SZ_XB + 8 * SZ_BGU_E + 8 * SZ_WDT_E + 8 * SZ_H_E;
  const size_t FULL_XG = HEAD + SZ_XG + 8 * SZ_BGU_E + 8 * SZ_WDT_E + 8 * SZ_H_E;

  float* rw = (float*)ws;
  int* cnt = (int*)(ws + SZ_RW);
  unsigned short* idx = (unsigned short*)(ws + SZ_RW + SZ_CNT);
  unsigned short* inv = (unsigned short*)(ws + SZ_RW + SZ_CNT + SZ_IDX);
  unsigned char* invn = (unsigned char*)(ws + SZ_RW + SZ_CNT + SZ_IDX + SZ_INV);

  router_kernel<<<BT_NUM, 256, 0, stream>>>(x, Wr, tp, rw);
  init_cnt_kernel<<<1, 64, 0, stream>>>(cnt);
  build_idx_kernel<<<16, 256, 0, stream>>>(rw, cnt, idx, inv, invn);
  pack_tiles_kernel<<<1, 64, 0, stream>>>(cnt);

  if (ws_size >= FULL_XG) {
    short* xg  = (short*)(ws + HEAD);
    char* rest = ws + HEAD + SZ_XG;
    short* Bgu = (short*)rest;
    short* WdT = (short*)(rest + 8 * SZ_BGU_E);
    short* h   = (short*)(rest + 8 * SZ_BGU_E + 8 * SZ_WDT_E);
    short* dout = Bgu;   // alias: Bgu dead after fused_gu

    gather_x_kernel<<<dim3(8, MAXT), 256, 0, stream>>>(x, idx, cnt, xg);
    transpose_cvt_kernel<<<dim3(64, 32, 24), dim3(32, 8), 0, stream>>>(
        Wg, Wu, Wd, Bgu, WdT, 8);
    fused_gu_kernel<1><<<dim3(16, MAXT), 512, 0, stream>>>(
        xg, Bgu, h, rw, idx, cnt, 0, 1);
    down_kernel<<<dim3(8, MAXT), 512, 0, stream>>>(h, WdT, dout, cnt);
    combine_kernel<<<BT_NUM, 256, 0, stream>>>(dout, inv, invn, out);
  } else if (ws_size >= FULL) {
    short* xb  = (short*)(ws + HEAD);
    char* rest = ws + HEAD + SZ_XB;
    short* Bgu = (short*)rest;
    short* WdT = (short*)(rest + 8 * SZ_BGU_E);
    short* h   = (short*)(rest + 8 * SZ_BGU_E + 8 * SZ_WDT_E);
    short* dout = Bgu;

    cvt_x_kernel<<<4096, 256, 0, stream>>>(x, xb);
    transpose_cvt_kernel<<<dim3(64, 32, 24), dim3(32, 8), 0, stream>>>(
        Wg, Wu, Wd, Bgu, WdT, 8);
    fused_gu_kernel<0><<<dim3(16, MAXT), 512, 0, stream>>>(
        xb, Bgu, h, rw, idx, cnt, 0, 1);
    down_kernel<<<dim3(8, MAXT), 512, 0, stream>>>(h, WdT, dout, cnt);
    combine_kernel<<<BT_NUM, 256, 0, stream>>>(dout, inv, invn, out);
  } else {
    short* xb  = (short*)(ws + HEAD);
    char* rest = ws + HEAD + SZ_XB;
    short* Bgu = (short*)rest;
    short* WdT = (short*)(rest + SZ_BGU_E);
    short* h   = (short*)(rest + SZ_BGU_E + SZ_WDT_E);

    cvt_x_kernel<<<4096, 256, 0, stream>>>(x, xb);
    zero_out_kernel<<<8192, 256, 0, stream>>>(out);
    for (int e = 0; e < 8; e++) {
      transpose_cvt_kernel<<<dim3(64, 32, 3), dim3(32, 8), 0, stream>>>(
          Wg + (size_t)e * MAT_ELEMS, Wu + (size_t)e * MAT_ELEMS,
          Wd + (size_t)e * MAT_ELEMS, Bgu, WdT, 1);
      fused_gu_kernel<0><<<dim3(16, 16), 512, 0, stream>>>(
          xb, Bgu, h, rw, idx, cnt, e, 0);
      down_atomic_kernel<<<dim3(8, 16), 512, 0, stream>>>(
          h, WdT, out, idx, cnt, e);
    }
  }
}